// Round 11
// baseline (334.082 us; speedup 1.0000x reference)
//
#include <hip/hip_runtime.h>
#include <hip/hip_bf16.h>

// ---------------------------------------------------------------------------
// Split pipeline:
//   K1 conv_embed : R8 kernel (~89us, VALU-issue-bound).
//   K2 gru_mfma   : WAVE-INDEPENDENT MFMA GRU. 64 blocks x 64 thr; each wave
//     owns 16 batch elements end-to-end: all 192 gate outputs per step via
//     12 N-tiles x mfma_f32_16x16x32_f16 (K=96: h|x). No cross-wave exchange,
//     NO __syncthreads in the recurrence (R10 post-mortem: 1-2 barriers/step
//     + LDS drain were ~60% of GRU time). h C-layout -> A-layout transpose
//     through LDS is wave-synchronous (in-order DS + wave_barrier fence).
// ---------------------------------------------------------------------------

#define B_    1024
#define L_    30
#define H_    64

typedef _Float16 half_t;
typedef __attribute__((ext_vector_type(8))) _Float16 half8;
typedef __attribute__((ext_vector_type(4))) float f32x4;

#define MFMA16(A, B, C) __builtin_amdgcn_mfma_f32_16x16x32_f16(A, B, C, 0, 0, 0)

__device__ __forceinline__ float sigmoid_f(float v) {
    return __builtin_amdgcn_rcpf(1.f + __expf(-v));
}
__device__ __forceinline__ float tanh_f(float v) {
    v = fminf(fmaxf(v, -15.f), 15.f);
    const float e = __expf(2.f * v);
    return (e - 1.f) * __builtin_amdgcn_rcpf(e + 1.f);
}
__device__ __forceinline__ void load4_lds(float* r, const float* p) {
    float2 a = *(const float2*)p;
    float2 b = *(const float2*)(p + 2);
    r[0] = a.x; r[1] = a.y; r[2] = b.x; r[3] = b.y;
}

// ---------------------------------------------------------------------------
// Kernel A: per-image conv encoder + fc. One 64-thread block per image.
// (unchanged — measured ~89us, VALUBusy ~100%)
// ---------------------------------------------------------------------------
__global__ __launch_bounds__(64) void conv_embed_kernel(
    const float* __restrict__ bbox,
    const float* __restrict__ head,
    const float* __restrict__ c1w, const float* __restrict__ c1b,
    const float* __restrict__ c2w, const float* __restrict__ c2b,
    const float* __restrict__ fcw, const float* __restrict__ fcb,
    float* __restrict__ enc_in)
{
    const int img = blockIdx.x;          // 0..30719
    const int b = img / L_;
    const int l = img % L_;
    const int tid = threadIdx.x;

    __shared__ float s_img[32 * 32];
    __shared__ float s_p1[4 * 15 * 16];  // [c][py][px], width padded to 16
    __shared__ float s_p2[360];
    __shared__ float s_red[60];

    {
        const float4* src = (const float4*)(head + ((size_t)b * 31 + (size_t)l) * 1024);
        float4* dst = (float4*)s_img;
        #pragma unroll
        for (int i = 0; i < 4; ++i) dst[tid + 64 * i] = src[tid + 64 * i];
    }
    __syncthreads();

    if (tid < 60) {
        const int c = tid / 15, px = tid % 15;
        const int x0 = 2 * px;
        float wg[9];
        #pragma unroll
        for (int k = 0; k < 9; ++k) wg[k] = c1w[c * 9 + k];
        const float bias = c1b[c];

        auto c1out = [&](const float* ra, const float* rb, const float* rc, const float* rd) -> float {
            float a00 = bias, a01 = bias, a10 = bias, a11 = bias;
            #pragma unroll
            for (int kx = 0; kx < 3; ++kx) {
                const float w0 = wg[kx], w1 = wg[3 + kx], w2 = wg[6 + kx];
                a00 = fmaf(w0, ra[kx],     fmaf(w1, rb[kx],     fmaf(w2, rc[kx],     a00)));
                a01 = fmaf(w0, ra[kx + 1], fmaf(w1, rb[kx + 1], fmaf(w2, rc[kx + 1], a01)));
                a10 = fmaf(w0, rb[kx],     fmaf(w1, rc[kx],     fmaf(w2, rd[kx],     a10)));
                a11 = fmaf(w0, rb[kx + 1], fmaf(w1, rc[kx + 1], fmaf(w2, rd[kx + 1], a11)));
            }
            a00 = fmaxf(a00, 0.f); a01 = fmaxf(a01, 0.f);
            a10 = fmaxf(a10, 0.f); a11 = fmaxf(a11, 0.f);
            return fmaxf(fmaxf(a00, a01), fmaxf(a10, a11));
        };

        float r[6][4];
        load4_lds(r[0], s_img + 0 * 32 + x0);
        load4_lds(r[1], s_img + 1 * 32 + x0);
        #pragma unroll
        for (int i = 0; i < 7; ++i) {
            const int s0 = (4 * i) % 6, s1 = (4 * i + 1) % 6, s2 = (4 * i + 2) % 6;
            const int s3 = (4 * i + 3) % 6, s4 = (4 * i + 4) % 6, s5 = (4 * i + 5) % 6;
            load4_lds(r[s2], s_img + (4 * i + 2) * 32 + x0);
            load4_lds(r[s3], s_img + (4 * i + 3) * 32 + x0);
            s_p1[c * 240 + (2 * i) * 16 + px] = c1out(r[s0], r[s1], r[s2], r[s3]);
            load4_lds(r[s4], s_img + (4 * i + 4) * 32 + x0);
            load4_lds(r[s5], s_img + (4 * i + 5) * 32 + x0);
            s_p1[c * 240 + (2 * i + 1) * 16 + px] = c1out(r[s2], r[s3], r[s4], r[s5]);
        }
        load4_lds(r[0], s_img + 30 * 32 + x0);
        load4_lds(r[1], s_img + 31 * 32 + x0);
        s_p1[c * 240 + 14 * 16 + px] = c1out(r[4], r[5], r[0], r[1]);
    }
    __syncthreads();

    if (tid < 60) {
        const int c = tid / 6, px = tid % 6;
        const int x0 = 2 * px;
        float wg2[4][9];
        #pragma unroll
        for (int ic = 0; ic < 4; ++ic)
            #pragma unroll
            for (int k = 0; k < 9; ++k) wg2[ic][k] = c2w[(c * 4 + ic) * 9 + k];
        const float bias2 = c2b[c];

        float P[6][4][4];
        auto c2out = [&](float (*pa)[4], float (*pb)[4], float (*pc)[4], float (*pd)[4]) -> float {
            float a00 = bias2, a01 = bias2, a10 = bias2, a11 = bias2;
            #pragma unroll
            for (int ic = 0; ic < 4; ++ic) {
                #pragma unroll
                for (int kx = 0; kx < 3; ++kx) {
                    const float w0 = wg2[ic][kx], w1 = wg2[ic][3 + kx], w2 = wg2[ic][6 + kx];
                    a00 = fmaf(w0, pa[ic][kx],     fmaf(w1, pb[ic][kx],     fmaf(w2, pc[ic][kx],     a00)));
                    a01 = fmaf(w0, pa[ic][kx + 1], fmaf(w1, pb[ic][kx + 1], fmaf(w2, pc[ic][kx + 1], a01)));
                    a10 = fmaf(w0, pb[ic][kx],     fmaf(w1, pc[ic][kx],     fmaf(w2, pd[ic][kx],     a10)));
                    a11 = fmaf(w0, pb[ic][kx + 1], fmaf(w1, pc[ic][kx + 1], fmaf(w2, pd[ic][kx + 1], a11)));
                }
            }
            a00 = fmaxf(a00, 0.f); a01 = fmaxf(a01, 0.f);
            a10 = fmaxf(a10, 0.f); a11 = fmaxf(a11, 0.f);
            return fmaxf(fmaxf(a00, a01), fmaxf(a10, a11));
        };

        #pragma unroll
        for (int ic = 0; ic < 4; ++ic) {
            load4_lds(P[0][ic], s_p1 + ic * 240 + 0 * 16 + x0);
            load4_lds(P[1][ic], s_p1 + ic * 240 + 1 * 16 + x0);
        }
        #pragma unroll
        for (int i = 0; i < 3; ++i) {
            const int s0 = (4 * i) % 6, s1 = (4 * i + 1) % 6, s2 = (4 * i + 2) % 6;
            const int s3 = (4 * i + 3) % 6, s4 = (4 * i + 4) % 6, s5 = (4 * i + 5) % 6;
            #pragma unroll
            for (int ic = 0; ic < 4; ++ic) {
                load4_lds(P[s2][ic], s_p1 + ic * 240 + (4 * i + 2) * 16 + x0);
                load4_lds(P[s3][ic], s_p1 + ic * 240 + (4 * i + 3) * 16 + x0);
            }
            s_p2[c * 36 + (2 * i) * 6 + px] = c2out(P[s0], P[s1], P[s2], P[s3]);
            #pragma unroll
            for (int ic = 0; ic < 4; ++ic) {
                load4_lds(P[s4][ic], s_p1 + ic * 240 + (4 * i + 4) * 16 + x0);
                load4_lds(P[s5][ic], s_p1 + ic * 240 + (4 * i + 5) * 16 + x0);
            }
            s_p2[c * 36 + (2 * i + 1) * 6 + px] = c2out(P[s2], P[s3], P[s4], P[s5]);
        }
    }
    __syncthreads();

    if (tid < 60) {
        const int o = tid / 12, i0 = tid % 12;
        const float* wrow = fcw + o * 360;
        float acc = 0.f;
        #pragma unroll
        for (int k = 0; k < 30; ++k) {
            const int i = i0 + 12 * k;
            acc = fmaf(wrow[i], s_p2[i], acc);
        }
        s_red[tid] = acc;
    }
    __syncthreads();

    float* dst = enc_in + ((size_t)b * L_ + l) * 9;
    if (tid < 5) {
        float acc = fcb[tid];
        #pragma unroll
        for (int k = 0; k < 12; ++k) acc += s_red[tid * 12 + k];
        dst[4 + tid] = acc;
    } else if (tid >= 8 && tid < 12) {
        const int d = tid - 8;
        const float* bb = bbox + (size_t)b * 124 + (size_t)l * 4;
        dst[d] = bb[4 + d] - bb[d];
    }
}

// ---------------------------------------------------------------------------
// Kernel B: wave-independent MFMA GRU. 64 blocks x 64 threads (ONE wave),
// 16 batches per wave, all 192 gate units computed by the wave itself.
// No __syncthreads in the loops; h transpose via wave-synchronous LDS.
// Layouts (guide §3, verified in R10): A[m=lane&15][k=quad*8+j];
// C/D col=lane&15 (N), row=quad*4+reg (M).
// ---------------------------------------------------------------------------
__global__ __launch_bounds__(64, 1) void gru_mfma_kernel(
    const float* __restrict__ bbox,     // [1024][31][4]
    const float* __restrict__ enc_in,   // [1024][30][9]
    const float* __restrict__ ewih, const float* __restrict__ ewhh,
    const float* __restrict__ ebih, const float* __restrict__ ebhh,
    const float* __restrict__ dwih, const float* __restrict__ dwhh,
    const float* __restrict__ dbih, const float* __restrict__ dbhh,
    const float* __restrict__ linw, const float* __restrict__ linb,
    float* __restrict__ out)            // [1024][20][4]
{
    const int bb   = blockIdx.x * 16;   // first batch of this wave
    const int lane = threadIdx.x;       // 0..63
    const int q    = lane >> 4;         // quad
    const int col  = lane & 15;

    // hA rows padded 64->72 halves so A-frag b128 reads spread banks.
    alignas(16) __shared__ half_t hA[16][72];        // h, A-layout [batch][k]
    alignas(16) __shared__ half_t xenc[30][16][40];  // [t][batch][k-64] (0..8 = x)
    alignas(16) __shared__ half_t xdec[16][40];      // [batch][k-64]   (0..3 = x)

    // ---- zero LDS (single wave; DS ops are in-order within a wave) ---------
    {
        int4* p = (int4*)hA;
        for (int i = lane; i < (int)(sizeof(hA) / 16); i += 64) p[i] = int4{0, 0, 0, 0};
        p = (int4*)xenc;
        for (int i = lane; i < (int)(sizeof(xenc) / 16); i += 64) p[i] = int4{0, 0, 0, 0};
        p = (int4*)xdec;
        for (int i = lane; i < (int)(sizeof(xdec) / 16); i += 64) p[i] = int4{0, 0, 0, 0};
    }

    // ---- stage encoder x into A-frag layout --------------------------------
    for (int pr = lane; pr < 480; pr += 64) {
        const int t = pr / 16, b = pr % 16;
        const float* src = enc_in + ((size_t)(bb + b) * L_ + t) * 9;
        #pragma unroll
        for (int d = 0; d < 9; ++d) xenc[t][b][d] = (half_t)src[d];
    }

    // ---- decoder x0 / offsets / cumsum (lanes col<4 own (batch q*4+r, d=col))
    float xold[4], ofs[4], cs[4];
    if (col < 4) {
        #pragma unroll
        for (int r = 0; r < 4; ++r) {
            const float* bbp = bbox + (size_t)(bb + q * 4 + r) * 124;
            xold[r] = bbp[120 + col] - bbp[116 + col];
            ofs[r]  = bbp[120 + col];
            cs[r]   = 0.f;
            xdec[q * 4 + r][col] = (half_t)xold[r];
        }
    }
    __builtin_amdgcn_wave_barrier();

    // ---- weight fragment builders (register-resident f16) ------------------
    // B[k][n] = W[n_global][k]; lane k = kap*32 + q*8 + j, n_global = g*64+nt*16+col
    auto h_frag = [&](const float* W, int g, int nt, int kap) -> half8 {
        const float* rp = W + (size_t)(g * 64 + nt * 16 + col) * 64 + kap * 32 + q * 8;
        half8 f;
        #pragma unroll
        for (int j = 0; j < 8; ++j) f[j] = (half_t)rp[j];
        return f;
    };
    auto x_frag = [&](const float* W, int g, int nt, int indim) -> half8 {
        half8 f;
        #pragma unroll
        for (int j = 0; j < 8; ++j) {
            const int d = q * 8 + j;
            f[j] = (d < indim) ? (half_t)W[(size_t)(g * 64 + nt * 16 + col) * indim + d]
                               : (half_t)0.f;
        }
        return f;
    };

    float hold[4][4];   // [nt][r] — h for (batch q*4+r, unit nt*16+col)
    #pragma unroll
    for (int nt = 0; nt < 4; ++nt)
        #pragma unroll
        for (int r = 0; r < 4; ++r) hold[nt][r] = 0.f;

    // =================== encoder: 30 steps, no barriers ====================
    {
        half8 eh[3][4][2], ex[3][4];
        #pragma unroll
        for (int g = 0; g < 3; ++g)
            #pragma unroll
            for (int nt = 0; nt < 4; ++nt) {
                eh[g][nt][0] = h_frag(ewhh, g, nt, 0);
                eh[g][nt][1] = h_frag(ewhh, g, nt, 1);
                ex[g][nt]    = x_frag(ewih, g, nt, 9);
            }
        float br[4], bz[4], bnh[4], bni[4];
        #pragma unroll
        for (int nt = 0; nt < 4; ++nt) {
            const int u = nt * 16 + col;
            br[nt]  = ebih[u]       + ebhh[u];
            bz[nt]  = ebih[64 + u]  + ebhh[64 + u];
            bnh[nt] = ebhh[128 + u];
            bni[nt] = ebih[128 + u];
        }

        #pragma unroll 1
        for (int t = 0; t < L_; ++t) {
            const half8 a0 = *(const half8*)&hA[col][q * 8];
            const half8 a1 = *(const half8*)&hA[col][32 + q * 8];
            const half8 a2 = *(const half8*)&xenc[t][col][q * 8];

            #pragma unroll
            for (int nt = 0; nt < 4; ++nt) {
                f32x4 Cr  = {br[nt], br[nt], br[nt], br[nt]};
                f32x4 Cz  = {bz[nt], bz[nt], bz[nt], bz[nt]};
                f32x4 Cnh = {bnh[nt], bnh[nt], bnh[nt], bnh[nt]};
                f32x4 Cnx = {bni[nt], bni[nt], bni[nt], bni[nt]};
                Cr  = MFMA16(a0, eh[0][nt][0], Cr);
                Cr  = MFMA16(a1, eh[0][nt][1], Cr);
                Cr  = MFMA16(a2, ex[0][nt],    Cr);
                Cz  = MFMA16(a0, eh[1][nt][0], Cz);
                Cz  = MFMA16(a1, eh[1][nt][1], Cz);
                Cz  = MFMA16(a2, ex[1][nt],    Cz);
                Cnh = MFMA16(a0, eh[2][nt][0], Cnh);
                Cnh = MFMA16(a1, eh[2][nt][1], Cnh);
                Cnx = MFMA16(a2, ex[2][nt],    Cnx);

                #pragma unroll
                for (int r = 0; r < 4; ++r) {
                    const float rr = sigmoid_f(Cr[r]);
                    const float zz = sigmoid_f(Cz[r]);
                    const float nn = tanh_f(Cnx[r] + rr * Cnh[r]);
                    hold[nt][r] = fmaf(zz, hold[nt][r] - nn, nn);
                    hA[q * 4 + r][nt * 16 + col] = (half_t)hold[nt][r];
                }
            }
            __builtin_amdgcn_wave_barrier();   // fence: keep writes before next reads
        }
    }

    // =================== decoder: 20 steps + lin + cumsum ==================
    {
        half8 dh[3][4][2], dx[3][4];
        #pragma unroll
        for (int g = 0; g < 3; ++g)
            #pragma unroll
            for (int nt = 0; nt < 4; ++nt) {
                dh[g][nt][0] = h_frag(dwhh, g, nt, 0);
                dh[g][nt][1] = h_frag(dwhh, g, nt, 1);
                dx[g][nt]    = x_frag(dwih, g, nt, 4);
            }
        float br[4], bz[4], bnh[4], bni[4];
        #pragma unroll
        for (int nt = 0; nt < 4; ++nt) {
            const int u = nt * 16 + col;
            br[nt]  = dbih[u]       + dbhh[u];
            bz[nt]  = dbih[64 + u]  + dbhh[64 + u];
            bnh[nt] = dbhh[128 + u];
            bni[nt] = dbih[128 + u];
        }
        half8 Bl0, Bl1;   // lin head: B[k][n] = linw[n][k], n = col (<4)
        #pragma unroll
        for (int j = 0; j < 8; ++j) {
            Bl0[j] = (col < 4) ? (half_t)linw[col * 64 +      q * 8 + j] : (half_t)0.f;
            Bl1[j] = (col < 4) ? (half_t)linw[col * 64 + 32 + q * 8 + j] : (half_t)0.f;
        }
        const float lb = (col < 4) ? linb[col] : 0.f;

        #pragma unroll 1
        for (int tt = 0; tt < 20; ++tt) {
            const half8 a0 = *(const half8*)&hA[col][q * 8];
            const half8 a1 = *(const half8*)&hA[col][32 + q * 8];
            const half8 a2 = *(const half8*)&xdec[col][q * 8];

            #pragma unroll
            for (int nt = 0; nt < 4; ++nt) {
                f32x4 Cr  = {br[nt], br[nt], br[nt], br[nt]};
                f32x4 Cz  = {bz[nt], bz[nt], bz[nt], bz[nt]};
                f32x4 Cnh = {bnh[nt], bnh[nt], bnh[nt], bnh[nt]};
                f32x4 Cnx = {bni[nt], bni[nt], bni[nt], bni[nt]};
                Cr  = MFMA16(a0, dh[0][nt][0], Cr);
                Cr  = MFMA16(a1, dh[0][nt][1], Cr);
                Cr  = MFMA16(a2, dx[0][nt],    Cr);
                Cz  = MFMA16(a0, dh[1][nt][0], Cz);
                Cz  = MFMA16(a1, dh[1][nt][1], Cz);
                Cz  = MFMA16(a2, dx[1][nt],    Cz);
                Cnh = MFMA16(a0, dh[2][nt][0], Cnh);
                Cnh = MFMA16(a1, dh[2][nt][1], Cnh);
                Cnx = MFMA16(a2, dx[2][nt],    Cnx);

                #pragma unroll
                for (int r = 0; r < 4; ++r) {
                    const float rr = sigmoid_f(Cr[r]);
                    const float zz = sigmoid_f(Cz[r]);
                    const float nn = tanh_f(Cnx[r] + rr * Cnh[r]);
                    hold[nt][r] = fmaf(zz, hold[nt][r] - nn, nn);
                    hA[q * 4 + r][nt * 16 + col] = (half_t)hold[nt][r];
                }
            }
            __builtin_amdgcn_wave_barrier();   // h_new writes before lin reads

            // lin head: X[batch][d] = h_new . linw[d]
            const half8 al0 = *(const half8*)&hA[col][q * 8];
            const half8 al1 = *(const half8*)&hA[col][32 + q * 8];
            f32x4 X = {0.f, 0.f, 0.f, 0.f};
            X = MFMA16(al0, Bl0, X);
            X = MFMA16(al1, Bl1, X);

            if (col < 4) {
                #pragma unroll
                for (int r = 0; r < 4; ++r) {
                    const float xv = X[r] + lb + xold[r];
                    xold[r] = xv;
                    cs[r] += xv;
                    xdec[q * 4 + r][col] = (half_t)xv;
                    out[(size_t)(bb + q * 4 + r) * 80 + tt * 4 + col] = cs[r] + ofs[r];
                }
            }
            __builtin_amdgcn_wave_barrier();   // xdec writes before next reads
        }
    }
}

// ---------------------------------------------------------------------------
extern "C" void kernel_launch(void* const* d_in, const int* in_sizes, int n_in,
                              void* d_out, int out_size, void* d_ws, size_t ws_size,
                              hipStream_t stream) {
    (void)in_sizes; (void)n_in; (void)out_size; (void)ws_size;
    const float* bbox = (const float*)d_in[0];
    const float* head = (const float*)d_in[1];
    const float* c1w  = (const float*)d_in[2];
    const float* c1b  = (const float*)d_in[3];
    const float* c2w  = (const float*)d_in[4];
    const float* c2b  = (const float*)d_in[5];
    const float* fcw  = (const float*)d_in[6];
    const float* fcb  = (const float*)d_in[7];
    const float* ewih = (const float*)d_in[8];
    const float* ewhh = (const float*)d_in[9];
    const float* ebih = (const float*)d_in[10];
    const float* ebhh = (const float*)d_in[11];
    const float* dwih = (const float*)d_in[12];
    const float* dwhh = (const float*)d_in[13];
    const float* dbih = (const float*)d_in[14];
    const float* dbhh = (const float*)d_in[15];
    const float* linw = (const float*)d_in[16];
    const float* linb = (const float*)d_in[17];
    float* out = (float*)d_out;

    float* enc_in = (float*)d_ws;   // 1024*30*9 floats

    conv_embed_kernel<<<B_ * L_, 64, 0, stream>>>(bbox, head, c1w, c1b, c2w, c2b,
                                                  fcw, fcb, enc_in);
    gru_mfma_kernel<<<B_ / 16, 64, 0, stream>>>(bbox, enc_in,
                                                ewih, ewhh, ebih, ebhh,
                                                dwih, dwhh, dbih, dbhh,
                                                linw, linb, out);
}